// Round 4
// baseline (559.631 us; speedup 1.0000x reference)
//
#include <hip/hip_runtime.h>
#include <math.h>

#define DUR 32
#define DIM 256
#define TT  528   // sum_b (32-b)

// ws float layout (ws is ~1 GiB; the harness fill proves it)
#define WS_G    0          // [256][528]  raw gelu outputs g[o][t]
#define WS_S    (256*TT)   // [528]       in-proj row sums

__device__ __forceinline__ float gelu_exact(float v) {
    return 0.5f * v * (1.0f + erff(v * 0.70710678118654752f));
}

__device__ __forceinline__ float wave_reduce_down(float v) {
    v += __shfl_down(v, 32, 64);
    v += __shfl_down(v, 16, 64);
    v += __shfl_down(v, 8, 64);
    v += __shfl_down(v, 4, 64);
    v += __shfl_down(v, 2, 64);
    v += __shfl_down(v, 1, 64);
    return v;   // lane 0 holds the sum
}

// One wave owns one (b, o) pair. No LDS, no barriers, NO atomics.
// Templated only on K4 (8 instantiations ~ 20KB code total, I$-resident).
// t blocked by 8 (static acc[8]); t8 and chunk loops are real runtime loops
// so the ~300-instr body is re-executed (hot-loop I$), not straight-line.
template<int K4>
__device__ __forceinline__ void wave_body(
    const int bb, const int o, const int lane,
    const float* __restrict__ x, const float* __restrict__ W,
    const float* __restrict__ convb, float* __restrict__ gbuf)
{
    const int k = bb + 1;           // 4*K4-3 .. 4*K4
    const int L = DUR - bb;
    constexpr int XN = 4 * K4 + 7;  // x window per t8-block (>= k+7)

    const float* Wo = W + (size_t)(bb * DIM + o) * (DIM * DUR);

    float mine = 0.f;
    const int nT8 = (L + 7) >> 3;
#pragma unroll 1
    for (int t8 = 0; t8 < nT8; ++t8) {
        const int t0 = t8 * 8;
        float acc[8];
#pragma unroll
        for (int j = 0; j < 8; ++j) acc[j] = 0.f;

#pragma unroll 1
        for (int c = 0; c < 4; ++c) {
            const int i = c * 64 + lane;
            const float* Wl = Wo + (size_t)i * DUR;
            float4 w4[K4];
#pragma unroll
            for (int m = 0; m < K4; ++m) w4[m] = *(const float4*)(Wl + 4 * m);
            // zero quad tail beyond k (runtime k, uniform in wave)
#pragma unroll
            for (int m = 0; m < K4; ++m) {
                if (4 * m + 1 >= k) w4[m].y = 0.f;
                if (4 * m + 2 >= k) w4[m].z = 0.f;
                if (4 * m + 3 >= k) w4[m].w = 0.f;
            }
            // x window: taus t0..t0+XN-1, clamped (clamped taps only feed
            // garbage t >= L, which is never consumed). Coalesced, L2-hit.
            float xv[XN];
#pragma unroll
            for (int j = 0; j < XN; ++j) {
                int tau = t0 + j; tau = (tau < 31) ? tau : 31;
                xv[j] = x[tau * DIM + i];
            }
#pragma unroll
            for (int j = 0; j < 8; ++j) {
#pragma unroll
                for (int m = 0; m < K4; ++m) {
                    acc[j] = fmaf(xv[j + 4*m + 0], w4[m].x, acc[j]);
                    acc[j] = fmaf(xv[j + 4*m + 1], w4[m].y, acc[j]);
                    acc[j] = fmaf(xv[j + 4*m + 2], w4[m].z, acc[j]);
                    acc[j] = fmaf(xv[j + 4*m + 3], w4[m].w, acc[j]);
                }
            }
        }
        // reduce each acc[j] over 64 lanes; deposit total at lane t0+j
#pragma unroll
        for (int j = 0; j < 8; ++j) {
            float v = acc[j];
            v += __shfl_xor(v, 1, 64);
            v += __shfl_xor(v, 2, 64);
            v += __shfl_xor(v, 4, 64);
            v += __shfl_xor(v, 8, 64);
            v += __shfl_xor(v, 16, 64);
            v += __shfl_xor(v, 32, 64);
            if (lane == t0 + j) mine = v;
        }
    }

    // epilogue: gelu, plain store (branches partition [0,528) per o -> no race)
    const int tg = bb * DUR - (bb * (bb - 1)) / 2;
    if (lane < L) {
        const float g = gelu_exact(mine + convb[bb * DIM + o]);
        gbuf[(size_t)o * TT + tg + lane] = g;
    }
}

__global__ __launch_bounds__(256, 4) void conv_kernel(
    const float* __restrict__ x, const float* __restrict__ W,
    const float* __restrict__ convb, float* __restrict__ ws)
{
    const int bid = blockIdx.x;
    // block-uniform class: bijective over the 32 classes within each o-group,
    // scrambled so one CU's resident blocks get well-spread classes.
    const int bb   = (13 * ((bid & 31) + (bid >> 8))) & 31;
    const int o    = (bid >> 5) * 4 + (threadIdx.x >> 6);
    const int lane = threadIdx.x & 63;
    float* gbuf = ws + WS_G;
    switch (bb >> 2) {   // K4 = (bb>>2)+1
        case 0:  wave_body<1>(bb, o, lane, x, W, convb, gbuf); break;
        case 1:  wave_body<2>(bb, o, lane, x, W, convb, gbuf); break;
        case 2:  wave_body<3>(bb, o, lane, x, W, convb, gbuf); break;
        case 3:  wave_body<4>(bb, o, lane, x, W, convb, gbuf); break;
        case 4:  wave_body<5>(bb, o, lane, x, W, convb, gbuf); break;
        case 5:  wave_body<6>(bb, o, lane, x, W, convb, gbuf); break;
        case 6:  wave_body<7>(bb, o, lane, x, W, convb, gbuf); break;
        default: wave_body<8>(bb, o, lane, x, W, convb, gbuf); break;
    }
}

// Phase A: reduce g over o -> per-t {cy_raw, cw, cb, gsum, gsq} in LDS
// (each block redundantly; blocks run in parallel, L2-resident data).
// Phase B: LN stats per branch, cc[t]; then GEMV rows. 132 blocks x 4 rows.
__global__ __launch_bounds__(256) void proj1_kernel(
    const float* __restrict__ ws_g, float* __restrict__ ws_s,
    const float* __restrict__ lnw, const float* __restrict__ lnb,
    const float* __restrict__ in_proj_w, const float* __restrict__ in_proj_b)
{
    __shared__ float cyr[TT], cwv[TT], cbv[TT], gs1[TT], gs2[TT];
    __shared__ float mu_s[32], r_s[32];
    const int n = threadIdx.x;

    for (int t = n; t < TT; t += 256) {
        int b = 0, off = 0;
        while (t >= off + (DUR - b)) { off += DUR - b; ++b; }
        const int tt = t - off;
        const float* lw = lnw + (size_t)b * DIM * DUR + tt;
        const float* lb = lnb + (size_t)b * DIM * DUR + tt;
        const float* gp = ws_g + t;
        float a_cy = 0.f, a_cw = 0.f, a_cb = 0.f, a_s1 = 0.f, a_s2 = 0.f;
#pragma unroll 4
        for (int o = 0; o < 256; ++o) {
            const float g = gp[(size_t)o * TT];
            const float w = lw[(size_t)o * DUR];
            a_cy = fmaf(g, w, a_cy);
            a_cw += w;
            a_cb += lb[(size_t)o * DUR];
            a_s1 += g;
            a_s2 = fmaf(g, g, a_s2);
        }
        cyr[t] = a_cy; cwv[t] = a_cw; cbv[t] = a_cb; gs1[t] = a_s1; gs2[t] = a_s2;
    }
    __syncthreads();
    if (n < 32) {
        const int b = n, Lb = DUR - b;
        const int off = b * DUR - (b * (b - 1)) / 2;
        float s1 = 0.f, s2 = 0.f;
        for (int t = 0; t < Lb; ++t) { s1 += gs1[off + t]; s2 += gs2[off + t]; }
        const float cnt = 256.f * (float)Lb;
        const float mu = s1 / cnt;
        mu_s[n] = mu;
        r_s[n] = rsqrtf(s2 / cnt - mu * mu + 1e-5f);
    }
    __syncthreads();
    for (int t = n; t < TT; t += 256) {
        int b = 0, off = 0;
        while (t >= off + (DUR - b)) { off += DUR - b; ++b; }
        cyr[t] = (cyr[t] - mu_s[b] * cwv[t]) * r_s[b] + cbv[t];   // cc[t]
    }
    __syncthreads();
    const int wave = n >> 6, lane = n & 63;
    const int row = blockIdx.x * 4 + wave;
    const float* Wr = in_proj_w + (size_t)(2 * TT + row) * TT;
    float a = 0.f;
    for (int t = lane; t < TT; t += 64) a = fmaf(Wr[t], cyr[t], a);
    a = wave_reduce_down(a);
    if (lane == 0) ws_s[row] = a + 256.f * in_proj_b[2 * TT + row];
}

// merged proj2a+proj2b: block w computes its 32 rows u = w*128 + j, then the
// mean, then broadcasts out[w*256 + d]. 4 blocks.
__global__ __launch_bounds__(256) void proj2_kernel(
    const float* __restrict__ ws_s, const float* __restrict__ out_proj_w,
    const float* __restrict__ out_proj_b, float* __restrict__ out)
{
    const int w = blockIdx.x, n = threadIdx.x;
    const int wave = n >> 6, lane = n & 63;
    __shared__ float s2s[32];
    __shared__ float mv;
    for (int jj = 0; jj < 8; ++jj) {
        const int j = wave * 8 + jj;
        const int u = w * 128 + j;
        const float* Or = out_proj_w + (size_t)u * TT;
        float a = 0.f;
        for (int t = lane; t < TT; t += 64) a = fmaf(Or[t], ws_s[t], a);
        a = wave_reduce_down(a);
        if (lane == 0) s2s[j] = a + 256.f * out_proj_b[u];
    }
    __syncthreads();
    if (n < 64) {
        float v = (n < 32) ? s2s[n] : 0.f;
        v += __shfl_down(v, 16, 64);
        v += __shfl_down(v, 8, 64);
        v += __shfl_down(v, 4, 64);
        v += __shfl_down(v, 2, 64);
        v += __shfl_down(v, 1, 64);
        if (n == 0) mv = v * (1.0f / 32.0f);
    }
    __syncthreads();
    out[w * 256 + n] = mv;
}

extern "C" void kernel_launch(void* const* d_in, const int* in_sizes, int n_in,
                              void* d_out, int out_size, void* d_ws, size_t ws_size,
                              hipStream_t stream)
{
    const float* x   = (const float*)d_in[0];
    const float* W   = (const float*)d_in[1];
    const float* cb  = (const float*)d_in[2];
    const float* lnw = (const float*)d_in[3];
    const float* lnb = (const float*)d_in[4];
    const float* ipw = (const float*)d_in[5];
    const float* ipb = (const float*)d_in[6];
    const float* opw = (const float*)d_in[7];
    const float* opb = (const float*)d_in[8];
    float* ws  = (float*)d_ws;
    float* out = (float*)d_out;

    conv_kernel<<<2048, 256, 0, stream>>>(x, W, cb, ws);
    proj1_kernel<<<132, 256, 0, stream>>>(ws + WS_G, ws + WS_S, lnw, lnb, ipw, ipb);
    proj2_kernel<<<4, 256, 0, stream>>>(ws + WS_S, opw, opb, out);
}

// Round 5
// 506.932 us; speedup vs baseline: 1.1040x; 1.1040x over previous
//
#include <hip/hip_runtime.h>
#include <math.h>

#define DUR 32
#define DIM 256
#define TT  528   // sum_b (32-b)

// ws float layout
#define WS_BSUM 0       // [32]   branch sums
#define WS_BSQ  32      // [32]   branch sumsq
#define WS_CY   64      // [528]  column sums of g*lnw
#define WS_CW   592     // [528]  sum_o lnw
#define WS_CB   1120    // [528]  sum_o lnb
#define WS_S    1648    // [528]  in-proj row sums
#define WS_ZERO_FLOATS 592   // BSUM+BSQ+CY

__device__ __forceinline__ float gelu_exact(float v) {
    return 0.5f * v * (1.0f + erff(v * 0.70710678118654752f));
}

__device__ __forceinline__ float wave_reduce_down(float v) {
    v += __shfl_down(v, 32, 64);
    v += __shfl_down(v, 16, 64);
    v += __shfl_down(v, 8, 64);
    v += __shfl_down(v, 4, 64);
    v += __shfl_down(v, 2, 64);
    v += __shfl_down(v, 1, 64);
    return v;   // lane 0 holds the sum
}

// One wave owns one (b, o) pair. Runtime bb within a compile-time K4 class:
// K4 = (bb>>2)+1, k = bb+1 in (4*K4-4, 4*K4], L = 32-bb, MAXL = 36-4*K4 (<=32).
// Single pass over W (fetch = 145MB minimum), register double-buffered chunks.
template<int K4>
__device__ __forceinline__ void wave_body(
    const int bb, const int o, const int lane,
    const float* __restrict__ x, const float* __restrict__ W,
    const float* __restrict__ convb, const float* __restrict__ lnw,
    float* __restrict__ ws)
{
    const int k = bb + 1;
    const int L = DUR - bb;
    constexpr int MAXL = (36 - 4 * K4) > 32 ? 32 : (36 - 4 * K4);

    const float* Wo = W + (size_t)(bb * DIM + o) * (DIM * DUR);

    float4 wb[2][K4];
    {   // prologue: chunk 0 loads
        const float* Wl = Wo + (size_t)lane * DUR;
#pragma unroll
        for (int m = 0; m < K4; ++m) wb[0][m] = *(const float4*)(Wl + 4 * m);
    }

    float acc[MAXL];
#pragma unroll
    for (int t = 0; t < MAXL; ++t) acc[t] = 0.f;

#pragma unroll 1
    for (int c = 0; c < 4; ++c) {
        const int cur = c & 1;
        if (c < 3) {   // next chunk's W loads stay in flight under compute
            const float* Wl = Wo + (size_t)((c + 1) * 64 + lane) * DUR;
#pragma unroll
            for (int m = 0; m < K4; ++m) wb[cur ^ 1][m] = *(const float4*)(Wl + 4 * m);
        }
        const int i = c * 64 + lane;
        // x column: 64 lanes read 256 consecutive bytes per tau (L2-resident)
        float xv[35];
#pragma unroll
        for (int tau = 0; tau < 32; ++tau) xv[tau] = x[tau * DIM + i];
        xv[32] = 0.f; xv[33] = 0.f; xv[34] = 0.f;   // masked-tap targets
        // mask quad tail beyond k in place (buffer is dead after this iter)
#pragma unroll
        for (int m = 0; m < K4; ++m) {
            if (4 * m + 1 >= k) wb[cur][m].y = 0.f;
            if (4 * m + 2 >= k) wb[cur][m].z = 0.f;
            if (4 * m + 3 >= k) wb[cur][m].w = 0.f;
        }
#pragma unroll
        for (int t = 0; t < MAXL; ++t) {
            if (t < L) {   // uniform runtime guard; acc stays in regs
#pragma unroll
                for (int m = 0; m < K4; ++m) {
                    acc[t] = fmaf(xv[t + 4*m + 0], wb[cur][m].x, acc[t]);
                    acc[t] = fmaf(xv[t + 4*m + 1], wb[cur][m].y, acc[t]);
                    acc[t] = fmaf(xv[t + 4*m + 2], wb[cur][m].z, acc[t]);
                    acc[t] = fmaf(xv[t + 4*m + 3], wb[cur][m].w, acc[t]);
                }
            }
        }
    }

    // butterfly-reduce each acc[t] over 64 lanes; lane t keeps total
    float mine = 0.f;
#pragma unroll
    for (int t = 0; t < MAXL; ++t) {
        if (t < L) {
            float v = acc[t];
            v += __shfl_xor(v, 1, 64);
            v += __shfl_xor(v, 2, 64);
            v += __shfl_xor(v, 4, 64);
            v += __shfl_xor(v, 8, 64);
            v += __shfl_xor(v, 16, 64);
            v += __shfl_xor(v, 32, 64);
            if (lane == t) mine = v;
        }
    }

    const int tg = bb * DUR - (bb * (bb - 1)) / 2;
    float g = 0.f;
    if (lane < L) {
        const float y = mine + convb[bb * DIM + o];
        g = gelu_exact(y);
        const float lw = lnw[((size_t)(bb * DIM + o)) * DUR + lane];
        atomicAdd(ws + WS_CY + tg + lane, g * lw);
    }
    const float s1 = wave_reduce_down(g);
    const float s2 = wave_reduce_down(g * g);
    if (lane == 0) {
        atomicAdd(ws + WS_BSUM + bb, s1);
        atomicAdd(ws + WS_BSQ  + bb, s2);
    }
}

// blocks [0,2048): conv. Class-paired for load balance: block bid -> pair
// p = bid&15; waves 0,1 run class p, waves 2,3 run class 31-p. Since
// K4(p)+K4(31-p) == 9 for all p, every block moves identical W-bytes.
// blocks [2048, 2048+528): CW/CB column sums (fill the conv tail).
__global__ __launch_bounds__(256, 4) void conv_kernel(
    const float* __restrict__ x, const float* __restrict__ W,
    const float* __restrict__ convb, const float* __restrict__ lnw,
    const float* __restrict__ lnb, float* __restrict__ ws)
{
    const int bid = blockIdx.x;
    const int n = threadIdx.x;
    if (bid >= 2048) {
        const int pb = bid - 2048;          // 0..527
        int b = 0, off = 0;
        while (pb >= off + (DUR - b)) { off += DUR - b; ++b; }
        const int t = pb - off;
        const float lw = lnw[((size_t)(b * DIM + n)) * DUR + t];
        const float lb = lnb[((size_t)(b * DIM + n)) * DUR + t];
        __shared__ float rw[4], rb[4];
        const int wave = n >> 6, lane = n & 63;
        const float a = wave_reduce_down(lw);
        const float c = wave_reduce_down(lb);
        if (lane == 0) { rw[wave] = a; rb[wave] = c; }
        __syncthreads();
        if (n == 0) {
            ws[WS_CW + pb] = rw[0] + rw[1] + rw[2] + rw[3];
            ws[WS_CB + pb] = rb[0] + rb[1] + rb[2] + rb[3];
        }
        return;
    }

    const int p    = bid & 15;
    const int og   = bid >> 4;              // 0..127
    const int w    = n >> 6;
    const int lane = n & 63;
    const int bb   = (w < 2) ? p : 31 - p;
    const int o    = og * 2 + (w & 1);
    switch (bb >> 2) {   // K4 = (bb>>2)+1
        case 0:  wave_body<1>(bb, o, lane, x, W, convb, lnw, ws); break;
        case 1:  wave_body<2>(bb, o, lane, x, W, convb, lnw, ws); break;
        case 2:  wave_body<3>(bb, o, lane, x, W, convb, lnw, ws); break;
        case 3:  wave_body<4>(bb, o, lane, x, W, convb, lnw, ws); break;
        case 4:  wave_body<5>(bb, o, lane, x, W, convb, lnw, ws); break;
        case 5:  wave_body<6>(bb, o, lane, x, W, convb, lnw, ws); break;
        case 6:  wave_body<7>(bb, o, lane, x, W, convb, lnw, ws); break;
        default: wave_body<8>(bb, o, lane, x, W, convb, lnw, ws); break;
    }
}

// c[t] from LN stats + colsums, then s = Wv @ c + 256*bv. 132 blocks x 4 rows.
__global__ __launch_bounds__(256) void proj1_kernel(
    float* ws, const float* __restrict__ in_proj_w,
    const float* __restrict__ in_proj_b)
{
    __shared__ float cc[TT];
    __shared__ float mu_s[32], r_s[32];
    __shared__ int map[TT];
    const int n = threadIdx.x;
    if (n < 32) {
        const int Lb = 32 - n;
        const float cnt = 256.f * (float)Lb;
        const float mu = ws[WS_BSUM + n] / cnt;
        const float var = ws[WS_BSQ + n] / cnt - mu * mu;
        mu_s[n] = mu;
        r_s[n] = rsqrtf(var + 1e-5f);
        const int off = n * 32 - (n * (n - 1)) / 2;
        for (int t = 0; t < Lb; ++t) map[off + t] = n;
    }
    __syncthreads();
    for (int t = n; t < TT; t += 256) {
        const int b = map[t];
        cc[t] = (ws[WS_CY + t] - mu_s[b] * ws[WS_CW + t]) * r_s[b] + ws[WS_CB + t];
    }
    __syncthreads();
    const int wave = n >> 6, lane = n & 63;
    const int row = blockIdx.x * 4 + wave;
    const float* Wr = in_proj_w + (size_t)(2 * TT + row) * TT;
    float a = 0.f;
    for (int t = lane; t < TT; t += 64) a = fmaf(Wr[t], cc[t], a);
    a = wave_reduce_down(a);
    if (lane == 0) ws[WS_S + row] = a + 256.f * in_proj_b[2 * TT + row];
}

// merged proj2a+proj2b: block w computes its 32 rows u = w*128 + j, then the
// mean, then broadcasts out[w*256 + d]. 4 blocks.
__global__ __launch_bounds__(256) void proj2_kernel(
    const float* __restrict__ ws, const float* __restrict__ out_proj_w,
    const float* __restrict__ out_proj_b, float* __restrict__ out)
{
    const int w = blockIdx.x, n = threadIdx.x;
    const int wave = n >> 6, lane = n & 63;
    __shared__ float s2s[32];
    __shared__ float mv;
    for (int jj = 0; jj < 8; ++jj) {
        const int j = wave * 8 + jj;
        const int u = w * 128 + j;
        const float* Or = out_proj_w + (size_t)u * TT;
        float a = 0.f;
        for (int t = lane; t < TT; t += 64) a = fmaf(Or[t], ws[WS_S + t], a);
        a = wave_reduce_down(a);
        if (lane == 0) s2s[j] = a + 256.f * out_proj_b[u];
    }
    __syncthreads();
    if (n < 64) {
        float v = (n < 32) ? s2s[n] : 0.f;
        v += __shfl_down(v, 16, 64);
        v += __shfl_down(v, 8, 64);
        v += __shfl_down(v, 4, 64);
        v += __shfl_down(v, 2, 64);
        v += __shfl_down(v, 1, 64);
        if (n == 0) mv = v * (1.0f / 32.0f);
    }
    __syncthreads();
    out[w * 256 + n] = mv;
}

extern "C" void kernel_launch(void* const* d_in, const int* in_sizes, int n_in,
                              void* d_out, int out_size, void* d_ws, size_t ws_size,
                              hipStream_t stream)
{
    const float* x   = (const float*)d_in[0];
    const float* W   = (const float*)d_in[1];
    const float* cb  = (const float*)d_in[2];
    const float* lnw = (const float*)d_in[3];
    const float* lnb = (const float*)d_in[4];
    const float* ipw = (const float*)d_in[5];
    const float* ipb = (const float*)d_in[6];
    const float* opw = (const float*)d_in[7];
    const float* opb = (const float*)d_in[8];
    float* ws  = (float*)d_ws;
    float* out = (float*)d_out;

    hipMemsetAsync(ws, 0, WS_ZERO_FLOATS * sizeof(float), stream);
    conv_kernel<<<2048 + TT, 256, 0, stream>>>(x, W, cb, lnw, lnb, ws);
    proj1_kernel<<<132, 256, 0, stream>>>(ws, ipw, ipb);
    proj2_kernel<<<4, 256, 0, stream>>>(ws, opw, opb, out);
}

// Round 6
// 454.565 us; speedup vs baseline: 1.2311x; 1.1152x over previous
//
#include <hip/hip_runtime.h>
#include <math.h>

#define DUR 32
#define DIM 256
#define TT  528   // sum_b (32-b)

// ws float layout
#define WS_BSUM 0       // [32]   branch sums
#define WS_BSQ  32      // [32]   branch sumsq
#define WS_CY   64      // [528]  column sums of g*lnw
#define WS_CW   592     // [528]  sum_o lnw
#define WS_CB   1120    // [528]  sum_o lnb
#define WS_S    1648    // [528]  in-proj row sums
#define WS_ZERO_FLOATS 592   // BSUM+BSQ+CY

__device__ __forceinline__ float gelu_exact(float v) {
    return 0.5f * v * (1.0f + erff(v * 0.70710678118654752f));
}

__device__ __forceinline__ float wave_reduce_down(float v) {
    v += __shfl_down(v, 32, 64);
    v += __shfl_down(v, 16, 64);
    v += __shfl_down(v, 8, 64);
    v += __shfl_down(v, 4, 64);
    v += __shfl_down(v, 2, 64);
    v += __shfl_down(v, 1, 64);
    return v;   // lane 0 holds the sum
}

// One wave owns one (b, o) pair. Runtime bb within compile-time K4 class:
// K4 = (bb>>2)+1, k = bb+1, L = 32-bb <= MAXL = 36-4*K4 (<=32).
// Hand-unrolled chunk pipeline with two STATICALLY-NAMED buffers (rule #20:
// no runtime index into a register array). asm-pins stop load sinking.
template<int K4>
__device__ __forceinline__ void wave_body(
    const int bb, const int o, const int lane,
    const float* __restrict__ x, const float* __restrict__ W,
    const float* __restrict__ convb, const float* __restrict__ lnw,
    float* __restrict__ ws)
{
    const int k = bb + 1;
    const int L = DUR - bb;
    constexpr int MAXL = (36 - 4 * K4) > 32 ? 32 : (36 - 4 * K4);

    const float* Wo = W + (size_t)(bb * DIM + o) * (DIM * DUR);

    float acc[MAXL];
#pragma unroll
    for (int t = 0; t < MAXL; ++t) acc[t] = 0.f;

    float4 wa[K4], wb2[K4];

#define LOAD_CHUNK(BUF, C)                                                   \
    {                                                                        \
        const float* Wl = Wo + (size_t)((C) * 64 + lane) * DUR;              \
        _Pragma("unroll")                                                    \
        for (int m = 0; m < K4; ++m) BUF[m] = *(const float4*)(Wl + 4 * m);  \
    }

#define COMPUTE_CHUNK(BUF, C)                                                \
    {                                                                        \
        const int i = (C) * 64 + lane;                                       \
        float xv[35];                                                        \
        _Pragma("unroll")                                                    \
        for (int tau = 0; tau < 32; ++tau) xv[tau] = x[tau * DIM + i];       \
        xv[32] = 0.f; xv[33] = 0.f; xv[34] = 0.f;                            \
        _Pragma("unroll")                                                    \
        for (int tau = 0; tau < 35; ++tau) asm volatile("" : "+v"(xv[tau])); \
        _Pragma("unroll")                                                    \
        for (int m = 0; m < K4; ++m) {                                       \
            if (4 * m + 1 >= k) BUF[m].y = 0.f;                              \
            if (4 * m + 2 >= k) BUF[m].z = 0.f;                              \
            if (4 * m + 3 >= k) BUF[m].w = 0.f;                              \
            asm volatile("" : "+v"(BUF[m].x), "+v"(BUF[m].y),                \
                              "+v"(BUF[m].z), "+v"(BUF[m].w));               \
        }                                                                    \
        _Pragma("unroll")                                                    \
        for (int t = 0; t < MAXL; ++t) {                                     \
            if (t < L) {                                                     \
                _Pragma("unroll")                                            \
                for (int m = 0; m < K4; ++m) {                               \
                    acc[t] = fmaf(xv[t + 4*m + 0], BUF[m].x, acc[t]);        \
                    acc[t] = fmaf(xv[t + 4*m + 1], BUF[m].y, acc[t]);        \
                    acc[t] = fmaf(xv[t + 4*m + 2], BUF[m].z, acc[t]);        \
                    acc[t] = fmaf(xv[t + 4*m + 3], BUF[m].w, acc[t]);        \
                }                                                            \
            }                                                                \
        }                                                                    \
    }

    LOAD_CHUNK(wa, 0)
    LOAD_CHUNK(wb2, 1)      // in flight under chunk-0 compute
    COMPUTE_CHUNK(wa, 0)
    LOAD_CHUNK(wa, 2)       // in flight under chunk-1 compute
    COMPUTE_CHUNK(wb2, 1)
    LOAD_CHUNK(wb2, 3)      // in flight under chunk-2 compute
    COMPUTE_CHUNK(wa, 2)
    COMPUTE_CHUNK(wb2, 3)

#undef LOAD_CHUNK
#undef COMPUTE_CHUNK

    // butterfly-reduce each acc[t] over 64 lanes; lane t keeps the total
    float mine = 0.f;
#pragma unroll
    for (int t = 0; t < MAXL; ++t) {
        if (t < L) {
            float v = acc[t];
            v += __shfl_xor(v, 1, 64);
            v += __shfl_xor(v, 2, 64);
            v += __shfl_xor(v, 4, 64);
            v += __shfl_xor(v, 8, 64);
            v += __shfl_xor(v, 16, 64);
            v += __shfl_xor(v, 32, 64);
            if (lane == t) mine = v;
        }
    }

    const int tg = bb * DUR - (bb * (bb - 1)) / 2;
    float g = 0.f;
    if (lane < L) {
        const float y = mine + convb[bb * DIM + o];
        g = gelu_exact(y);
        const float lw = lnw[((size_t)(bb * DIM + o)) * DUR + lane];
        atomicAdd(ws + WS_CY + tg + lane, g * lw);
    }
    const float s1 = wave_reduce_down(g);
    const float s2 = wave_reduce_down(g * g);
    if (lane == 0) {
        atomicAdd(ws + WS_BSUM + bb, s1);
        atomicAdd(ws + WS_BSQ  + bb, s2);
    }
}

// blocks [0,2048): conv. p = (bid>>3)&15 -> CU sees ONE class pair (bid and
// bid+256 share p under round-robin dispatch) => 2 hot template bodies per
// CU (I$-resident). Waves 0,1: class p; waves 2,3: class 31-p. Pair W-bytes
// are equal for all p (K4(p)+K4(31-p)==9).
// blocks [2048, 2048+528): CW/CB column sums (fill the conv tail).
__global__ __launch_bounds__(256, 3) void conv_kernel(
    const float* __restrict__ x, const float* __restrict__ W,
    const float* __restrict__ convb, const float* __restrict__ lnw,
    const float* __restrict__ lnb, float* __restrict__ ws)
{
    const int bid = blockIdx.x;
    const int n = threadIdx.x;
    if (bid >= 2048) {
        const int pb = bid - 2048;          // 0..527
        int b = 0, off = 0;
        while (pb >= off + (DUR - b)) { off += DUR - b; ++b; }
        const int t = pb - off;
        const float lw = lnw[((size_t)(b * DIM + n)) * DUR + t];
        const float lb = lnb[((size_t)(b * DIM + n)) * DUR + t];
        __shared__ float rw[4], rb[4];
        const int wave = n >> 6, lane = n & 63;
        const float a = wave_reduce_down(lw);
        const float c = wave_reduce_down(lb);
        if (lane == 0) { rw[wave] = a; rb[wave] = c; }
        __syncthreads();
        if (n == 0) {
            ws[WS_CW + pb] = rw[0] + rw[1] + rw[2] + rw[3];
            ws[WS_CB + pb] = rb[0] + rb[1] + rb[2] + rb[3];
        }
        return;
    }

    const int p    = (bid >> 3) & 15;
    const int og   = (bid & 7) | ((bid >> 7) << 3);   // 0..127
    const int w    = n >> 6;
    const int lane = n & 63;
    const int bb   = (w < 2) ? p : 31 - p;
    const int o    = og * 2 + (w & 1);
    switch (bb >> 2) {   // K4 = (bb>>2)+1
        case 0:  wave_body<1>(bb, o, lane, x, W, convb, lnw, ws); break;
        case 1:  wave_body<2>(bb, o, lane, x, W, convb, lnw, ws); break;
        case 2:  wave_body<3>(bb, o, lane, x, W, convb, lnw, ws); break;
        case 3:  wave_body<4>(bb, o, lane, x, W, convb, lnw, ws); break;
        case 4:  wave_body<5>(bb, o, lane, x, W, convb, lnw, ws); break;
        case 5:  wave_body<6>(bb, o, lane, x, W, convb, lnw, ws); break;
        case 6:  wave_body<7>(bb, o, lane, x, W, convb, lnw, ws); break;
        default: wave_body<8>(bb, o, lane, x, W, convb, lnw, ws); break;
    }
}

// c[t] from LN stats + colsums, then s = Wv @ c + 256*bv. 132 blocks x 4 rows.
__global__ __launch_bounds__(256) void proj1_kernel(
    float* ws, const float* __restrict__ in_proj_w,
    const float* __restrict__ in_proj_b)
{
    __shared__ float cc[TT];
    __shared__ float mu_s[32], r_s[32];
    __shared__ int map[TT];
    const int n = threadIdx.x;
    if (n < 32) {
        const int Lb = 32 - n;
        const float cnt = 256.f * (float)Lb;
        const float mu = ws[WS_BSUM + n] / cnt;
        const float var = ws[WS_BSQ + n] / cnt - mu * mu;
        mu_s[n] = mu;
        r_s[n] = rsqrtf(var + 1e-5f);
        const int off = n * 32 - (n * (n - 1)) / 2;
        for (int t = 0; t < Lb; ++t) map[off + t] = n;
    }
    __syncthreads();
    for (int t = n; t < TT; t += 256) {
        const int b = map[t];
        cc[t] = (ws[WS_CY + t] - mu_s[b] * ws[WS_CW + t]) * r_s[b] + ws[WS_CB + t];
    }
    __syncthreads();
    const int wave = n >> 6, lane = n & 63;
    const int row = blockIdx.x * 4 + wave;
    const float* Wr = in_proj_w + (size_t)(2 * TT + row) * TT;
    float a = 0.f;
    for (int t = lane; t < TT; t += 64) a = fmaf(Wr[t], cc[t], a);
    a = wave_reduce_down(a);
    if (lane == 0) ws[WS_S + row] = a + 256.f * in_proj_b[2 * TT + row];
}

// merged proj2a+proj2b: block w computes its 32 rows u = w*128 + j, then the
// mean, then broadcasts out[w*256 + d]. 4 blocks.
__global__ __launch_bounds__(256) void proj2_kernel(
    const float* __restrict__ ws, const float* __restrict__ out_proj_w,
    const float* __restrict__ out_proj_b, float* __restrict__ out)
{
    const int w = blockIdx.x, n = threadIdx.x;
    const int wave = n >> 6, lane = n & 63;
    __shared__ float s2s[32];
    __shared__ float mv;
    for (int jj = 0; jj < 8; ++jj) {
        const int j = wave * 8 + jj;
        const int u = w * 128 + j;
        const float* Or = out_proj_w + (size_t)u * TT;
        float a = 0.f;
        for (int t = lane; t < TT; t += 64) a = fmaf(Or[t], ws[WS_S + t], a);
        a = wave_reduce_down(a);
        if (lane == 0) s2s[j] = a + 256.f * out_proj_b[u];
    }
    __syncthreads();
    if (n < 64) {
        float v = (n < 32) ? s2s[n] : 0.f;
        v += __shfl_down(v, 16, 64);
        v += __shfl_down(v, 8, 64);
        v += __shfl_down(v, 4, 64);
        v += __shfl_down(v, 2, 64);
        v += __shfl_down(v, 1, 64);
        if (n == 0) mv = v * (1.0f / 32.0f);
    }
    __syncthreads();
    out[w * 256 + n] = mv;
}

extern "C" void kernel_launch(void* const* d_in, const int* in_sizes, int n_in,
                              void* d_out, int out_size, void* d_ws, size_t ws_size,
                              hipStream_t stream)
{
    const float* x   = (const float*)d_in[0];
    const float* W   = (const float*)d_in[1];
    const float* cb  = (const float*)d_in[2];
    const float* lnw = (const float*)d_in[3];
    const float* lnb = (const float*)d_in[4];
    const float* ipw = (const float*)d_in[5];
    const float* ipb = (const float*)d_in[6];
    const float* opw = (const float*)d_in[7];
    const float* opb = (const float*)d_in[8];
    float* ws  = (float*)d_ws;
    float* out = (float*)d_out;

    hipMemsetAsync(ws, 0, WS_ZERO_FLOATS * sizeof(float), stream);
    conv_kernel<<<2048 + TT, 256, 0, stream>>>(x, W, cb, lnw, lnb, ws);
    proj1_kernel<<<132, 256, 0, stream>>>(ws, ipw, ipb);
    proj2_kernel<<<4, 256, 0, stream>>>(ws, opw, opb, out);
}